// Round 17
// baseline (25.997 us; speedup 1.0000x reference)
//
#include <hip/hip_runtime.h>

// out[b,o] = sum_{i,n} (Ps*tanh(k*(x + Ec*bm)) + bias) * coef
// bm = 1 + c*sg; c = -0.4*sigmoid(-10*(x-prev)); sg = 1/(1+exp2(G*(x+Ec)))
// tanh(a) = 1 - 2*r, r = 1/(1+exp2(kt*inner)); out = base[o] - 2*sum pc*r
//
// R17: R16 (24.9us) is LDS-instruction-bound: 15 cyc/term (pl b128 + xp
// b128 + up b64 per 2 terms) = 12.8us/CU floor > VALU 10.5us/SIMD.
// This round: 9 cyc/term.
//  - up[] DELETED: gate exp2 via Schraudolph bit-trick (fma+cvt, full
//    rate, +-2.9% rel; basis exp2 likewise). Zero trans + zero u-read in
//    main loop. Error budget: dtanh <= ~2% worst, RMS ~0.3 over 1024
//    random-sign terms -> absmax ~1-1.6 (threshold 3.2).
//  - Param b128 amortized over TWO row-pairs (bpl, bpl+8): per 4 terms =
//    1 pl + 2 xp b128 = 36 cyc -> 9 cyc/term -> 7.7us/CU LDS floor.
//  - VALU ~25 pk-instr/pair ~ 5.3us/SIMD (stays under LDS).
//  - LDS 50.4KB; proven 512-block x 1024-thread x TILES=2 skeleton;
//    all reads conflict-free (pl 8nx16B; xp 8bplx16B, two 128B halves).

#define GATE_C 14.426950408889634f   // 10*log2(e)
#define TANH_C 2.8853900817779268f   // 2*log2(e)

typedef float f32x2 __attribute__((ext_vector_type(2)));
typedef float f32x4 __attribute__((ext_vector_type(4)));
typedef int   i32x2 __attribute__((ext_vector_type(2)));

constexpr int B = 512, I = 128, O = 64, NB = 8, BT = 32, TILES = 2;
constexpr int BP = BT / 2;   // 16 row-pairs per tile

__device__ __forceinline__ f32x2 pk_rcp1(f32x2 d) {   // d>0, ~1.2e-3 rel
  i32x2 yi = (i32x2)(0x7EF127EA) - __builtin_bit_cast(i32x2, d);
  f32x2 y = __builtin_bit_cast(f32x2, yi);
  return y * __builtin_elementwise_fma(-d, y, (f32x2)(2.f));
}
__device__ __forceinline__ f32x2 pk_rcp2(f32x2 d) {   // d>0, ~1.5e-6 rel
  i32x2 yi = (i32x2)(0x7EF127EA) - __builtin_bit_cast(i32x2, d);
  f32x2 y = __builtin_bit_cast(f32x2, yi);
  y = y * __builtin_elementwise_fma(-d, y, (f32x2)(2.f));
  return y * __builtin_elementwise_fma(-d, y, (f32x2)(2.f));
}
// Schraudolph exp2: bitcast((int)(t*2^23 + (127<<23) - 486411)), +-2.9% rel.
// Args bounded: |t| <= ~105 -> int in [5.7e8, 1.95e9], no overflow/subnormal.
__device__ __forceinline__ f32x2 pk_exp2s(f32x2 t) {
  f32x2 r;
  r.x = __int_as_float((int)fmaf(t.x, 8388608.f, 1064866805.f));
  r.y = __int_as_float((int)fmaf(t.y, 8388608.f, 1064866805.f));
  return r;
}

__global__ __launch_bounds__(1024, 4) void fe_main(
    const float* __restrict__ x, const float* __restrict__ k,
    const float* __restrict__ Ec, const float* __restrict__ Ps,
    const float* __restrict__ bias, const float* __restrict__ coef,
    float* __restrict__ out)
{
  __shared__ f32x4 pl[I][NB];      // {ec, G*ec, kt, pc}         16 KB
  __shared__ f32x4 xp[I][BP];      // {x_e, x_o, c_e, c_o}       32 KB
  __shared__ f32x4 racc[16][8];    // per-wave 4-row partials     2 KB
  __shared__ float red[16];        // base[o] partials

  const int tid = threadIdx.x;
  const int o   = blockIdx.y;
  const int n   = tid & 7;              // in-wave: branch
  const int bpl = (tid >> 3) & 7;       // in-wave: row-pair low index
  const int w   = tid >> 6;             // wave 0..15 = i-group

  // ---- params for this o (once per block) + base[o] partial ----
  {
    const int i = tid >> 3, nn = tid & 7;
    const int g = (i * O + o) * NB + nn;
    const float E = Ec[g], K = k[g], P = Ps[g], C = coef[g], Bs = bias[g];
    const float pc = P * C;
    pl[i][nn] = (f32x4){E, E * GATE_C, K * TANH_C, pc};
    float pbase = fmaf(Bs, C, pc);
    #pragma unroll
    for (int m = 1; m < 64; m <<= 1) pbase += __shfl_xor(pbase, m);
    if ((tid & 63) == 0) red[w] = pbase;
  }

  // body for one row-pair, packed f32x2; p in scope
  #define PAIR(ACC, Q) {                                                     \
    const f32x2 xx = Q.lo, cc = Q.hi;                                        \
    const f32x2 ta = __builtin_elementwise_fma(xx, (f32x2)(GATE_C),          \
                                               (f32x2)(p.y));                \
    const f32x2 d1 = pk_exp2s(ta) + (f32x2)(1.f);                            \
    const f32x2 sg = pk_rcp1(d1);                /* sigmoid(-10(x+Ec)) */    \
    const f32x2 bm = __builtin_elementwise_fma(cc, sg, (f32x2)(1.f));        \
    const f32x2 inr = __builtin_elementwise_fma((f32x2)(p.x), bm, xx);       \
    const f32x2 tb = (f32x2)(p.z) * inr;                                     \
    const f32x2 d2 = pk_exp2s(tb) + (f32x2)(1.f);                            \
    const f32x2 r = pk_rcp2(d2);                                             \
    ACC = __builtin_elementwise_fma((f32x2)(p.w), r, ACC); }

  for (int t = 0; t < TILES; ++t) {
    const int b0 = blockIdx.x * (BT * TILES) + t * BT;
    __syncthreads();   // params/red ready (t=0); xp/racc safe to reuse (t>0)

    // ---- stage row-pair-packed {x, c} (hw trans ok: 2 pairs/thread) ----
    for (int e = tid; e < I * BP; e += 1024) {
      const int bq = e & 15, i = e >> 4;
      const int re = b0 + 2 * bq;
      const float xe = x[re * I + i];
      const float xo = x[(re + 1) * I + i];
      const float xm = (re == 0) ? 0.f : x[(re - 1) * I + i];
      const float ce = -0.4f * __builtin_amdgcn_rcpf(
          1.f + __builtin_amdgcn_exp2f(GATE_C * (xe - xm)));
      const float co = -0.4f * __builtin_amdgcn_rcpf(
          1.f + __builtin_amdgcn_exp2f(GATE_C * (xo - xe)));
      xp[i][bq] = (f32x4){xe, xo, ce, co};
    }
    __syncthreads();

    // ---- main: 8 i's x 2 row-pairs; 1 param b128 per 4 terms ----
    f32x2 accL = (f32x2)(0.f), accH = (f32x2)(0.f);
    #pragma unroll
    for (int it = 0; it < 8; ++it) {
      const int i = w * 8 + it;
      const f32x4 p  = pl[i][n];        // broadcast over 8 n-lane groups
      const f32x4 qL = xp[i][bpl];      // conflict-free b128 (128B span)
      const f32x4 qH = xp[i][bpl + 8];  // conflict-free b128 (+128B)
      PAIR(accL, qL)
      PAIR(accH, qH)
    }

    // ---- reduce over n (in-wave), stash per (wave, bpl) ----
    #pragma unroll
    for (int m = 1; m < 8; m <<= 1) {
      accL.x += __shfl_xor(accL.x, m); accL.y += __shfl_xor(accL.y, m);
      accH.x += __shfl_xor(accH.x, m); accH.y += __shfl_xor(accH.y, m);
    }
    if (n == 0) racc[w][bpl] = (f32x4){accL.x, accL.y, accH.x, accH.y};
    __syncthreads();

    // ---- final: 32 threads, one output row each; sum 16 waves ----
    if (tid < 32) {
      const int pr = tid >> 1, sel = tid & 1;       // pair, elem
      const int bq = pr & 7, hi = (pr >> 3) * 2;    // low/high pair half
      float s = 0.f;
      #pragma unroll
      for (int ww = 0; ww < 16; ++ww)
        s += ((const float*)&racc[ww][bq])[hi + sel];
      float base = 0.f;
      #pragma unroll
      for (int q = 0; q < 16; ++q) base += red[q];
      out[(b0 + tid) * O + o] = fmaf(-2.f, s, base);
    }
  }
  #undef PAIR
}

extern "C" void kernel_launch(void* const* d_in, const int* in_sizes, int n_in,
                              void* d_out, int out_size, void* d_ws, size_t ws_size,
                              hipStream_t stream) {
  const float* x    = (const float*)d_in[0];
  const float* k    = (const float*)d_in[1];
  const float* Ec   = (const float*)d_in[2];
  const float* Ps   = (const float*)d_in[3];
  const float* bias = (const float*)d_in[4];
  const float* coef = (const float*)d_in[5];
  float* out = (float*)d_out;

  dim3 grid(B / (BT * TILES), O);   // (8, 64) = 512 blocks (proven best)
  fe_main<<<grid, 1024, 0, stream>>>(x, k, Ec, Ps, bias, coef, out);
}

// Round 18
// 24.583 us; speedup vs baseline: 1.0575x; 1.0575x over previous
//
#include <hip/hip_runtime.h>

// out[b,o] = sum_{i,n} (Ps*tanh(k*(x + Ec*bm)) + bias) * coef
// bm = 1 + c*sg; c = -0.4*sigmoid(-10*(x-prev)); sg = 1/(1+exp2(G*(x+Ec)))
// tanh(a) = 1 - 2*r, r = 1/(1+exp2(kt*inner)); out = base[o] - 2*sum pc*r
//
// R18: pipe models exhausted (R16 ~13us model / R17 ~9us model both
// measure ~25us; R10 saturated run matches models at 85% VALUBusy) =>
// single-pass is PHASE-SERIALIZATION bound: stage->barrier->compute per
// tile with 1-3 blocks/CU leaves barriers uncovered. Fix (T14):
//  - 256 blocks (4,64) = exactly 1/CU, no dispatch rounds, TILES=4
//    (param gather amortized 4x).
//  - Double-buffered xp: prefetch tile t+1's x into REGS before
//    compute(t) (phase A); trans+LDS-write after compute (phase D);
//    ONE barrier per tile (racc also double-buffered).
//  - Body = R17's packed 0-trans PAIR (validated absmax 0.75).
// Predict 20-22us; if ~25 persists, wall is harness-side (clock ramp).

#define GATE_C 14.426950408889634f   // 10*log2(e)
#define TANH_C 2.8853900817779268f   // 2*log2(e)

typedef float f32x2 __attribute__((ext_vector_type(2)));
typedef float f32x4 __attribute__((ext_vector_type(4)));
typedef int   i32x2 __attribute__((ext_vector_type(2)));

constexpr int B = 512, I = 128, O = 64, NB = 8, BT = 32, TILES = 4;
constexpr int BP = BT / 2;   // 16 row-pairs per tile

__device__ __forceinline__ f32x2 pk_rcp1(f32x2 d) {   // d>0, ~1.2e-3 rel
  i32x2 yi = (i32x2)(0x7EF127EA) - __builtin_bit_cast(i32x2, d);
  f32x2 y = __builtin_bit_cast(f32x2, yi);
  return y * __builtin_elementwise_fma(-d, y, (f32x2)(2.f));
}
__device__ __forceinline__ f32x2 pk_rcp2(f32x2 d) {   // d>0, ~1.5e-6 rel
  i32x2 yi = (i32x2)(0x7EF127EA) - __builtin_bit_cast(i32x2, d);
  f32x2 y = __builtin_bit_cast(f32x2, yi);
  y = y * __builtin_elementwise_fma(-d, y, (f32x2)(2.f));
  return y * __builtin_elementwise_fma(-d, y, (f32x2)(2.f));
}
// Schraudolph exp2: bitcast((int)(t*2^23 + (127<<23) - 486411)), +-2.9% rel.
__device__ __forceinline__ f32x2 pk_exp2s(f32x2 t) {
  f32x2 r;
  r.x = __int_as_float((int)fmaf(t.x, 8388608.f, 1064866805.f));
  r.y = __int_as_float((int)fmaf(t.y, 8388608.f, 1064866805.f));
  return r;
}

__global__ __launch_bounds__(1024, 4) void fe_main(
    const float* __restrict__ x, const float* __restrict__ k,
    const float* __restrict__ Ec, const float* __restrict__ Ps,
    const float* __restrict__ bias, const float* __restrict__ coef,
    float* __restrict__ out)
{
  __shared__ f32x4 pl[I][NB];        // {ec, G*ec, kt, pc}        16 KB
  __shared__ f32x4 xp[2][I][BP];     // {x_e,x_o,c_e,c_o} dbuf    64 KB
  __shared__ f32x4 racc[2][16][8];   // per-wave partials, dbuf    4 KB
  __shared__ float red[16];          // base[o] partials

  const int tid = threadIdx.x;
  const int o   = blockIdx.y;
  const int bbase = blockIdx.x * (BT * TILES);
  const int n   = tid & 7;              // in-wave: branch
  const int bpl = (tid >> 3) & 7;       // in-wave: row-pair low index
  const int w   = tid >> 6;             // wave 0..15 = i-group

  // ---- params for this o (once per block) + base[o] partial ----
  {
    const int i = tid >> 3, nn = tid & 7;
    const int g = (i * O + o) * NB + nn;
    const float E = Ec[g], K = k[g], P = Ps[g], C = coef[g], Bs = bias[g];
    const float pc = P * C;
    pl[i][nn] = (f32x4){E, E * GATE_C, K * TANH_C, pc};
    float pbase = fmaf(Bs, C, pc);
    #pragma unroll
    for (int m = 1; m < 64; m <<= 1) pbase += __shfl_xor(pbase, m);
    if ((tid & 63) == 0) red[w] = pbase;
  }

  // this thread's two staging slots (I*BP = 2048 entries / 1024 threads)
  const int sbq = tid & 15;             // row-pair index
  const int si0 = tid >> 4;             // i slot 0 (0..63)
  const int si1 = si0 + 64;             // i slot 1 (64..127)

  // ---- initial stage: tile 0 -> xp[0] (only place needing re==0 guard) ----
  {
    #pragma unroll
    for (int h = 0; h < 2; ++h) {
      const int i = h ? si1 : si0;
      const int re = bbase + 2 * sbq;
      const float xe = x[re * I + i];
      const float xo = x[(re + 1) * I + i];
      const float xm = (re == 0) ? 0.f : x[(re - 1) * I + i];
      const float ce = -0.4f * __builtin_amdgcn_rcpf(
          1.f + __builtin_amdgcn_exp2f(GATE_C * (xe - xm)));
      const float co = -0.4f * __builtin_amdgcn_rcpf(
          1.f + __builtin_amdgcn_exp2f(GATE_C * (xo - xe)));
      xp[0][i][sbq] = (f32x4){xe, xo, ce, co};
    }
  }
  __syncthreads();

  // body for one row-pair, packed f32x2; p in scope
  #define PAIR(ACC, Q) {                                                     \
    const f32x2 xx = Q.lo, cc = Q.hi;                                        \
    const f32x2 ta = __builtin_elementwise_fma(xx, (f32x2)(GATE_C),          \
                                               (f32x2)(p.y));                \
    const f32x2 d1 = pk_exp2s(ta) + (f32x2)(1.f);                            \
    const f32x2 sg = pk_rcp1(d1);                /* sigmoid(-10(x+Ec)) */    \
    const f32x2 bm = __builtin_elementwise_fma(cc, sg, (f32x2)(1.f));        \
    const f32x2 inr = __builtin_elementwise_fma((f32x2)(p.x), bm, xx);       \
    const f32x2 tb = (f32x2)(p.z) * inr;                                     \
    const f32x2 d2 = pk_exp2s(tb) + (f32x2)(1.f);                            \
    const f32x2 r = pk_rcp2(d2);                                             \
    ACC = __builtin_elementwise_fma((f32x2)(p.w), r, ACC); }

  for (int t = 0; t < TILES; ++t) {
    const int cur = t & 1;

    // (A) prefetch next tile's x rows into regs (latency hides under B)
    float pxe0, pxo0, pxm0, pxe1, pxo1, pxm1;
    if (t + 1 < TILES) {
      const int re = bbase + (t + 1) * BT + 2 * sbq;   // re >= 32: no guard
      pxe0 = x[re * I + si0]; pxo0 = x[(re + 1) * I + si0];
      pxm0 = x[(re - 1) * I + si0];
      pxe1 = x[re * I + si1]; pxo1 = x[(re + 1) * I + si1];
      pxm1 = x[(re - 1) * I + si1];
    }

    // (B) compute from xp[cur]: 8 i's x 2 row-pairs, 1 pl b128 / 4 terms
    f32x2 accL = (f32x2)(0.f), accH = (f32x2)(0.f);
    #pragma unroll
    for (int it = 0; it < 8; ++it) {
      const int i = w * 8 + it;
      const f32x4 p  = pl[i][n];        // broadcast over n-lanes
      const f32x4 qL = xp[cur][i][bpl];       // conflict-free b128
      const f32x4 qH = xp[cur][i][bpl + 8];   // conflict-free b128
      PAIR(accL, qL)
      PAIR(accH, qH)
    }

    // (C) reduce over n (in-wave), stash per (wave, bpl)
    #pragma unroll
    for (int m = 1; m < 8; m <<= 1) {
      accL.x += __shfl_xor(accL.x, m); accL.y += __shfl_xor(accL.y, m);
      accH.x += __shfl_xor(accH.x, m); accH.y += __shfl_xor(accH.y, m);
    }
    if (n == 0) racc[cur][w][bpl] = (f32x4){accL.x, accL.y, accH.x, accH.y};

    // (D) finish staging tile t+1 into xp[cur^1] (other buffer: race-free;
    //     readers of xp[cur^1] from tile t-1 all passed barrier t-1)
    if (t + 1 < TILES) {
      const float ce0 = -0.4f * __builtin_amdgcn_rcpf(
          1.f + __builtin_amdgcn_exp2f(GATE_C * (pxe0 - pxm0)));
      const float co0 = -0.4f * __builtin_amdgcn_rcpf(
          1.f + __builtin_amdgcn_exp2f(GATE_C * (pxo0 - pxe0)));
      xp[cur ^ 1][si0][sbq] = (f32x4){pxe0, pxo0, ce0, co0};
      const float ce1 = -0.4f * __builtin_amdgcn_rcpf(
          1.f + __builtin_amdgcn_exp2f(GATE_C * (pxe1 - pxm1)));
      const float co1 = -0.4f * __builtin_amdgcn_rcpf(
          1.f + __builtin_amdgcn_exp2f(GATE_C * (pxo1 - pxe1)));
      xp[cur ^ 1][si1][sbq] = (f32x4){pxe1, pxo1, ce1, co1};
    }

    __syncthreads();   // ONE barrier per tile

    // (F) output for tile t (first 32 threads; overlaps others' next A/B)
    if (tid < 32) {
      const int pr = tid >> 1, sel = tid & 1;
      const int bq = pr & 7, hi = (pr >> 3) * 2;
      float s = 0.f;
      #pragma unroll
      for (int ww = 0; ww < 16; ++ww)
        s += ((const float*)&racc[cur][ww][bq])[hi + sel];
      float base = 0.f;
      #pragma unroll
      for (int q = 0; q < 16; ++q) base += red[q];
      out[(bbase + t * BT + tid) * O + o] = fmaf(-2.f, s, base);
    }
  }
  #undef PAIR
}

extern "C" void kernel_launch(void* const* d_in, const int* in_sizes, int n_in,
                              void* d_out, int out_size, void* d_ws, size_t ws_size,
                              hipStream_t stream) {
  const float* x    = (const float*)d_in[0];
  const float* k    = (const float*)d_in[1];
  const float* Ec   = (const float*)d_in[2];
  const float* Ps   = (const float*)d_in[3];
  const float* bias = (const float*)d_in[4];
  const float* coef = (const float*)d_in[5];
  float* out = (float*)d_out;

  dim3 grid(B / (BT * TILES), O);   // (4, 64) = 256 blocks = 1 per CU
  fe_main<<<grid, 1024, 0, stream>>>(x, k, Ec, Ps, bias, coef, out);
}